// Round 2
// baseline (145.472 us; speedup 1.0000x reference)
//
#include <hip/hip_runtime.h>

// SimpleCRFHead R7: fused single-kernel quad-split forward-backward (R6
// resubmit, hardened). 512 blocks x 128 threads. Wave 0 = forward half
// (t=0..127), wave 1 = backward half (t=255..128) of the SAME 16 sequences;
// partials exchanged through LDS, combined in-block, out written directly.
// 3-buffer LDS ring, 2-window-deep prefetch, counted s_waitcnt
// vmcnt(32/16/0) -- steady state never drains to 0.
// Hardening vs R6: p255 is a direct per-lane register load pinned to the
// prologue (asm dummy use), iv[] pinned to the prologue -- no compiler
// global load (or its implicit vmcnt wait) can sink into the counted loop.
// Inner per-step math identical to R5 (absmax 0.0).

#define B_N 8192
#define L_N 256
#define SEQ_STRIDE 2304      // L_N * 9
#define HALF 128
#define SPB 6                // steps per x window
#define XW 54                // floats per seq per window
#define XSTRIDE 55           // odd -> conflict-free LDS banks
#define NBLK 22              // ceil(128/6)
#define PLS 129              // path LDS row stride
#define SPW 16               // seqs per block
#define NBLOCKS (B_N / SPW)  // 512

#define LOG2E 1.44269504088896340736f
#define LN2f  0.69314718055994530942f

// quad_perm rotate-left-by-r: lane c receives quad-lane (c+r)&3
#define QP1 57    // perm(1,2,3,0)
#define QP2 78    // perm(2,3,0,1)
#define QP3 147   // perm(3,0,1,2)
#define QROT(src, CTRL) \
  __int_as_float(__builtin_amdgcn_mov_dpp(__float_as_int(src), CTRL, 0xf, 0xf, 0))

#define WAITV(N) asm volatile("s_waitcnt vmcnt(" #N ")" ::: "memory")

__device__ __forceinline__ void gl_lds4(const void* g, void* l) {
  __builtin_amdgcn_global_load_lds(
      (const __attribute__((address_space(1))) void*)g,
      (__attribute__((address_space(3))) void*)l, 4, 0, 0);
}

__device__ __forceinline__ float fexp(float x) {
  return __builtin_amdgcn_exp2f(x * LOG2E);   // v_exp_f32 = 2^x
}

__global__ __launch_bounds__(128, 1) void crf_fused(
    const float* __restrict__ xg, const int* __restrict__ path,
    const float* __restrict__ tran, const float* __restrict__ initv,
    float* __restrict__ out)
{
  __shared__ float lx[2][3][SPW * XSTRIDE];  // 21120 B (3-buffer ring)
  __shared__ int   pl[2][SPW * PLS];         // 16512 B
  __shared__ float ltran[2][81];
  __shared__ float comb[2][SPW][11];         // fwd/bwd partials for combine

  const int tid  = threadIdx.x;
  const int w    = tid >> 6;                 // wave: 0=fwd, 1=bwd
  const int lane = tid & 63;
  const int c = lane & 3;                    // quad slot (state group)
  const int q = lane >> 2;                   // seq slot within wave (0..15)
  const bool fwd = (w == 0);
  const int seq0 = blockIdx.x * SPW;

  // ---- phase 1: ALL compiler-tracked global loads, pinned here so none
  // sinks into the counted-vmcnt loop.
  for (int i = lane; i < 81; i += 64) ltran[w][i] = tran[i];

  // rotation-ordered transition coefficients (prologue only)
  // fwd: out_i = sum_j E[i][j]*st[j], E[i][j]=e^{tran[j*9+i]}
  // bwd: out_i = sum_j E[i][j]*w[j],  E[i][j]=e^{tran[i*9+j]}
  float Erot[4][3][3];
#pragma unroll
  for (int r = 0; r < 4; ++r)
#pragma unroll
    for (int k = 0; k < 3; ++k)
#pragma unroll
      for (int i = 0; i < 3; ++i) {
        const int ig = 3 * c + i;
        const int jg = 3 * ((c + r) & 3) + k;
        float v = 0.f;
        if (ig < 9 && jg < 9)
          v = fexp(fwd ? tran[jg * 9 + ig] : tran[ig * 9 + jg]);
        Erot[r][k][i] = v;
      }

  float iv[3];
#pragma unroll
  for (int k = 0; k < 3; ++k) {
    iv[k] = (fwd && c < 3) ? initv[3 * c + k] : 0.f;
    asm volatile("" :: "v"(iv[k]));          // pin materialization here
  }

  float o[3];
  float emit = 0.f, trn = 0.f;
  int ce = 0, pcur = 0;
  if (!fwd) {
#pragma unroll
    for (int k = 0; k < 3; ++k) o[k] = (c < 3) ? 1.f : 0.f;
    pcur = path[(size_t)(seq0 + q) * L_N + 255];   // p_255, direct
  }
  asm volatile("" :: "v"(pcur));             // pin load + its wait here
  const int myoff = (c == 3) ? 0 : 3 * c;

  // ---- phase 2: counted gl_lds staging (path rows + x windows 0,1)
  {
    const int t0 = fwd ? 0 : 127;
#pragma unroll
    for (int r = 0; r < SPW; ++r) {
      const int* g = path + (size_t)(seq0 + r) * L_N + t0 + lane;
      gl_lds4(g,      &pl[w][r * PLS]);       // 32 loads total
      gl_lds4(g + 64, &pl[w][r * PLS + 64]);
    }
  }
  if (lane < XW) {
#pragma unroll
    for (int wi = 0; wi < 2; ++wi) {
      const int fb = fwd ? wi * XW : (SEQ_STRIDE - XW * (wi + 1));
#pragma unroll
      for (int r = 0; r < SPW; ++r)
        gl_lds4(xg + (size_t)(seq0 + r) * SEQ_STRIDE + fb + lane,
                &lx[w][wi][r * XSTRIDE]);     // 16 loads per window
    }
  }

#pragma unroll 1
  for (int b = 0; b < NBLK; ++b) {
    // prefetch window b+2 into ring slot (b+2)%3, then counted wait:
    // steady state leaves windows b+1,b+2 (32 loads) in flight.
    if (b + 2 < NBLK) {
      if (lane < XW) {
        const int fb = fwd ? (b + 2) * XW : (SEQ_STRIDE - XW * (b + 3));
        float* dst = &lx[w][(b + 2) % 3][0];
#pragma unroll
        for (int r = 0; r < SPW; ++r)
          gl_lds4(xg + (size_t)(seq0 + r) * SEQ_STRIDE + fb + lane,
                  dst + r * XSTRIDE);
      }
      WAITV(32);              // drains through window b (FIFO retire)
    } else if (b + 1 < NBLK) {
      WAITV(16);              // only window b+1 may stay in flight
    } else {
      WAITV(0);               // last window
    }

    const float* lxq = &lx[w][b % 3][q * XSTRIDE];

    // ---- own-state exps for the whole window (3 per step)
    float e[SPB * 3];
#pragma unroll
    for (int tt = 0; tt < SPB; ++tt)
#pragma unroll
      for (int k = 0; k < 3; ++k)
        e[tt * 3 + k] = fexp(lxq[tt * 9 + myoff + k]);

    if (fwd) {
#pragma unroll
      for (int kk = 0; kk < SPB; ++kk) {
        const int t = b * SPB + kk;
        if (t < HALF) {
          if (t == 0) {
#pragma unroll
            for (int k = 0; k < 3; ++k)
              o[k] = (c < 3) ? fexp(iv[k] + lxq[myoff + k]) : 0.f;
            pcur = pl[w][q * PLS];
            emit = lxq[pcur];
          } else {
            float g[4][3];
#pragma unroll
            for (int k = 0; k < 3; ++k) {
              g[0][k] = o[k];
              g[1][k] = QROT(o[k], QP1);
              g[2][k] = QROT(o[k], QP2);
              g[3][k] = QROT(o[k], QP3);
            }
            if (kk == 0 && b > 0) {   // rescale once per window
              float m = g[0][0];
#pragma unroll
              for (int r = 0; r < 4; ++r)
#pragma unroll
                for (int k = 0; k < 3; ++k) m = fmaxf(m, g[r][k]);
              const int ex = (int)((__float_as_uint(m) >> 23) & 0xffu) - 126;
              ce += ex;
              const float sc = __uint_as_float((unsigned)(127 - ex) << 23);
#pragma unroll
              for (int r = 0; r < 4; ++r)
#pragma unroll
                for (int k = 0; k < 3; ++k) g[r][k] *= sc;
            }
            float out3[3];
#pragma unroll
            for (int i = 0; i < 3; ++i) {
              float a = Erot[0][0][i] * g[0][0];
#pragma unroll
              for (int r = 0; r < 4; ++r)
#pragma unroll
                for (int k = 0; k < 3; ++k)
                  if (r + k > 0) a = fmaf(Erot[r][k][i], g[r][k], a);
              out3[i] = a;
            }
            const int p = pl[w][q * PLS + t];
            emit += lxq[kk * 9 + p];
            trn  += ltran[w][pcur * 9 + p];
            pcur = p;
#pragma unroll
            for (int i = 0; i < 3; ++i) o[i] = out3[i] * e[kk * 3 + i];
          }
        }
      }
    } else {
#pragma unroll
      for (int kk = 0; kk < SPB; ++kk) {
        const int t = 255 - b * SPB - kk;
        if (t >= HALF) {
          const int tt = SPB - 1 - kk;
          float wv[3];
#pragma unroll
          for (int k = 0; k < 3; ++k) wv[k] = e[tt * 3 + k] * o[k];
          float g[4][3];
#pragma unroll
          for (int k = 0; k < 3; ++k) {
            g[0][k] = wv[k];
            g[1][k] = QROT(wv[k], QP1);
            g[2][k] = QROT(wv[k], QP2);
            g[3][k] = QROT(wv[k], QP3);
          }
          if (kk == 0 && b > 0) {
            float m = g[0][0];
#pragma unroll
            for (int r = 0; r < 4; ++r)
#pragma unroll
              for (int k = 0; k < 3; ++k) m = fmaxf(m, g[r][k]);
            const int ex = (int)((__float_as_uint(m) >> 23) & 0xffu) - 126;
            ce += ex;
            const float sc = __uint_as_float((unsigned)(127 - ex) << 23);
#pragma unroll
            for (int r = 0; r < 4; ++r)
#pragma unroll
              for (int k = 0; k < 3; ++k) g[r][k] *= sc;
          }
#pragma unroll
          for (int i = 0; i < 3; ++i) {
            float a = Erot[0][0][i] * g[0][0];
#pragma unroll
            for (int r = 0; r < 4; ++r)
#pragma unroll
              for (int k = 0; k < 3; ++k)
                if (r + k > 0) a = fmaf(Erot[r][k][i], g[r][k], a);
            o[i] = a;
          }
          emit += lxq[tt * 9 + pcur];
          const int pm = pl[w][q * PLS + (t - 1 - 127)];
          trn += ltran[w][pm * 9 + pcur];
          pcur = pm;
        }
      }
    }
  }

  // ---- exchange partials through LDS and combine in-block
  if (c < 3) {
#pragma unroll
    for (int k = 0; k < 3; ++k) comb[w][q][3 * c + k] = o[k];
  } else {
    comb[w][q][9]  = (float)ce;
    comb[w][q][10] = fwd ? (emit + trn + initv[pl[w][q * PLS]])
                         : (emit + trn);
  }
  __syncthreads();

  if (tid < SPW) {
    float dot = 0.f;
#pragma unroll
    for (int i = 0; i < 9; ++i)
      dot = fmaf(comb[0][tid][i], comb[1][tid][i], dot);
    const float score =
        (__builtin_amdgcn_logf(dot) + comb[0][tid][9] + comb[1][tid][9]) * LN2f;
    out[seq0 + tid] = score - (comb[0][tid][10] + comb[1][tid][10]);
  }
}

extern "C" void kernel_launch(void* const* d_in, const int* in_sizes, int n_in,
                              void* d_out, int out_size, void* d_ws, size_t ws_size,
                              hipStream_t stream) {
  (void)in_sizes; (void)n_in; (void)out_size; (void)d_ws; (void)ws_size;
  const float* xg    = (const float*)d_in[0];
  const int*   path  = (const int*)d_in[1];
  const float* tran  = (const float*)d_in[2];
  const float* initv = (const float*)d_in[3];
  float* out = (float*)d_out;

  crf_fused<<<NBLOCKS, 128, 0, stream>>>(xg, path, tran, initv, out);
}

// Round 3
// 145.454 us; speedup vs baseline: 1.0001x; 1.0001x over previous
//
#include <hip/hip_runtime.h>

// SimpleCRFHead R8: fused quad-split forward-backward, batched path-score.
// 512 blocks x 128 threads; wave 0 = fwd half (t=0..127), wave 1 = bwd half
// (t=255..128) of the same 16 seqs; combined in-block via LDS.
// vs R7: (1) path-score LDS reads batched per window -- 6 independent p
// loads (clamped addrs, no control deps), then 12 independent emit/tran
// loads, accumulate at window end. Removes the ~240cy/step dependent
// ds_read chain that caused VALUBusy=24%. (2) reverted 3-ring counted
// vmcnt to R5's proven 2-buffer vmcnt(0) schedule (prefetch issued one
// full window before its wait).
// Inner alpha math identical to R5/R7 (absmax 0.0).

#define B_N 8192
#define L_N 256
#define SEQ_STRIDE 2304      // L_N * 9
#define HALF 128
#define SPB 6                // steps per x window
#define XW 54                // floats per seq per window
#define XSTRIDE 55           // odd -> conflict-free LDS banks
#define NBLK 22              // ceil(128/6)
#define PLS 129              // path LDS row stride
#define SPW 16               // seqs per block
#define NBLOCKS (B_N / SPW)  // 512

#define LOG2E 1.44269504088896340736f
#define LN2f  0.69314718055994530942f

// quad_perm rotate-left-by-r: lane c receives quad-lane (c+r)&3
#define QP1 57    // perm(1,2,3,0)
#define QP2 78    // perm(2,3,0,1)
#define QP3 147   // perm(3,0,1,2)
#define QROT(src, CTRL) \
  __int_as_float(__builtin_amdgcn_mov_dpp(__float_as_int(src), CTRL, 0xf, 0xf, 0))

#define WAITV(N) asm volatile("s_waitcnt vmcnt(" #N ")" ::: "memory")

__device__ __forceinline__ void gl_lds4(const void* g, void* l) {
  __builtin_amdgcn_global_load_lds(
      (const __attribute__((address_space(1))) void*)g,
      (__attribute__((address_space(3))) void*)l, 4, 0, 0);
}

__device__ __forceinline__ float fexp(float x) {
  return __builtin_amdgcn_exp2f(x * LOG2E);   // v_exp_f32 = 2^x
}

__global__ __launch_bounds__(128, 1) void crf_fused(
    const float* __restrict__ xg, const int* __restrict__ path,
    const float* __restrict__ tran, const float* __restrict__ initv,
    float* __restrict__ out)
{
  __shared__ float lx[2][2][SPW * XSTRIDE];  // 14080 B (double buffer)
  __shared__ int   pl[2][SPW * PLS];         // 16512 B
  __shared__ float ltran[2][81];
  __shared__ float comb[2][SPW][11];         // fwd/bwd partials for combine

  const int tid  = threadIdx.x;
  const int w    = tid >> 6;                 // wave: 0=fwd, 1=bwd
  const int lane = tid & 63;
  const int c = lane & 3;                    // quad slot (state group)
  const int q = lane >> 2;                   // seq slot within wave (0..15)
  const bool fwd = (w == 0);
  const int seq0 = blockIdx.x * SPW;

  // ---- phase 1: all compiler-tracked global loads, pinned to prologue
  for (int i = lane; i < 81; i += 64) ltran[w][i] = tran[i];

  // rotation-ordered transition coefficients (prologue only)
  // fwd: out_i = sum_j E[i][j]*st[j], E[i][j]=e^{tran[j*9+i]}
  // bwd: out_i = sum_j E[i][j]*w[j],  E[i][j]=e^{tran[i*9+j]}
  float Erot[4][3][3];
#pragma unroll
  for (int r = 0; r < 4; ++r)
#pragma unroll
    for (int k = 0; k < 3; ++k)
#pragma unroll
      for (int i = 0; i < 3; ++i) {
        const int ig = 3 * c + i;
        const int jg = 3 * ((c + r) & 3) + k;
        float v = 0.f;
        if (ig < 9 && jg < 9)
          v = fexp(fwd ? tran[jg * 9 + ig] : tran[ig * 9 + jg]);
        Erot[r][k][i] = v;
      }

  float iv[3];
#pragma unroll
  for (int k = 0; k < 3; ++k) {
    iv[k] = (fwd && c < 3) ? initv[3 * c + k] : 0.f;
    asm volatile("" :: "v"(iv[k]));          // pin materialization here
  }

  float o[3];
  float emit = 0.f, trn = 0.f;
  int ce = 0, pcur = 0;
  if (!fwd) {
#pragma unroll
    for (int k = 0; k < 3; ++k) o[k] = (c < 3) ? 1.f : 0.f;
    pcur = path[(size_t)(seq0 + q) * L_N + 255];   // p_255, direct
  }
  asm volatile("" :: "v"(pcur));             // pin load + its wait here
  const int myoff = (c == 3) ? 0 : 3 * c;

  // ---- phase 2: gl_lds staging (path rows + x window 0)
  {
    const int t0 = fwd ? 0 : 127;
#pragma unroll
    for (int r = 0; r < SPW; ++r) {
      const int* g = path + (size_t)(seq0 + r) * L_N + t0 + lane;
      gl_lds4(g,      &pl[w][r * PLS]);
      gl_lds4(g + 64, &pl[w][r * PLS + 64]);
    }
  }
  if (lane < XW) {
    const int fb = fwd ? 0 : (SEQ_STRIDE - XW);
#pragma unroll
    for (int r = 0; r < SPW; ++r)
      gl_lds4(xg + (size_t)(seq0 + r) * SEQ_STRIDE + fb + lane,
              &lx[w][0][r * XSTRIDE]);
  }

  const int*   plr = &pl[w][q * PLS];
  const float* ltw = ltran[w];

#pragma unroll 1
  for (int b = 0; b < NBLK; ++b) {
    WAITV(0);                 // window b (and, at b=0, path rows) staged

    // prefetch window b+1 (waited one full window of compute later)
    if (b + 1 < NBLK && lane < XW) {
      const int fb = fwd ? (b + 1) * XW : (SEQ_STRIDE - XW * (b + 2));
      float* dst = &lx[w][(b + 1) & 1][0];
#pragma unroll
      for (int r = 0; r < SPW; ++r)
        gl_lds4(xg + (size_t)(seq0 + r) * SEQ_STRIDE + fb + lane,
                dst + r * XSTRIDE);
    }

    const float* lxq = &lx[w][b & 1][q * XSTRIDE];
    const int tb = b * SPB;

    // ---- batched path-score reads (all independent; clamped addresses)
    int p[SPB];
    if (fwd) {
#pragma unroll
      for (int kk = 0; kk < SPB; ++kk) {
        int t = tb + kk; if (t > HALF - 1) t = HALF - 1;
        p[kk] = plr[t];
      }
    } else {
#pragma unroll
      for (int kk = 0; kk < SPB; ++kk) {
        int idx = 127 - tb - kk; if (idx < 0) idx = 0;
        p[kk] = plr[idx];       // p_{t-1} for t = 255-tb-kk
      }
    }

    // ---- own-state exps for the whole window (3 per step)
    float e[SPB * 3];
#pragma unroll
    for (int tt = 0; tt < SPB; ++tt)
#pragma unroll
      for (int k = 0; k < 3; ++k)
        e[tt * 3 + k] = fexp(lxq[tt * 9 + myoff + k]);

    // ---- batched emit/tran reads (depend only on p[], all independent)
    float em[SPB], tr[SPB];
    if (fwd) {
#pragma unroll
      for (int kk = 0; kk < SPB; ++kk) {
        em[kk] = lxq[kk * 9 + p[kk]];
        const int pp = kk ? p[kk - 1] : pcur;
        tr[kk] = ltw[pp * 9 + p[kk]];
      }
    } else {
#pragma unroll
      for (int kk = 0; kk < SPB; ++kk) {
        const int pc = kk ? p[kk - 1] : pcur;
        em[kk] = lxq[(SPB - 1 - kk) * 9 + pc];
        tr[kk] = ltw[p[kk] * 9 + pc];
      }
    }
    pcur = p[SPB - 1];

    // ---- alpha recursion (register-only per step)
    if (fwd) {
#pragma unroll
      for (int kk = 0; kk < SPB; ++kk) {
        const int t = tb + kk;
        if (t < HALF) {
          if (t == 0) {
#pragma unroll
            for (int k = 0; k < 3; ++k)
              o[k] = (c < 3) ? fexp(iv[k] + lxq[myoff + k]) : 0.f;
          } else {
            float g[4][3];
#pragma unroll
            for (int k = 0; k < 3; ++k) {
              g[0][k] = o[k];
              g[1][k] = QROT(o[k], QP1);
              g[2][k] = QROT(o[k], QP2);
              g[3][k] = QROT(o[k], QP3);
            }
            if (kk == 0 && b > 0) {   // rescale once per window
              float m = g[0][0];
#pragma unroll
              for (int r = 0; r < 4; ++r)
#pragma unroll
                for (int k = 0; k < 3; ++k) m = fmaxf(m, g[r][k]);
              const int ex = (int)((__float_as_uint(m) >> 23) & 0xffu) - 126;
              ce += ex;
              const float sc = __uint_as_float((unsigned)(127 - ex) << 23);
#pragma unroll
              for (int r = 0; r < 4; ++r)
#pragma unroll
                for (int k = 0; k < 3; ++k) g[r][k] *= sc;
            }
            float out3[3];
#pragma unroll
            for (int i = 0; i < 3; ++i) {
              float a = Erot[0][0][i] * g[0][0];
#pragma unroll
              for (int r = 0; r < 4; ++r)
#pragma unroll
                for (int k = 0; k < 3; ++k)
                  if (r + k > 0) a = fmaf(Erot[r][k][i], g[r][k], a);
              out3[i] = a;
            }
#pragma unroll
            for (int i = 0; i < 3; ++i) o[i] = out3[i] * e[kk * 3 + i];
          }
        }
      }
    } else {
#pragma unroll
      for (int kk = 0; kk < SPB; ++kk) {
        const int t = 255 - tb - kk;
        if (t >= HALF) {
          const int tt = SPB - 1 - kk;
          float wv[3];
#pragma unroll
          for (int k = 0; k < 3; ++k) wv[k] = e[tt * 3 + k] * o[k];
          float g[4][3];
#pragma unroll
          for (int k = 0; k < 3; ++k) {
            g[0][k] = wv[k];
            g[1][k] = QROT(wv[k], QP1);
            g[2][k] = QROT(wv[k], QP2);
            g[3][k] = QROT(wv[k], QP3);
          }
          if (kk == 0 && b > 0) {
            float m = g[0][0];
#pragma unroll
            for (int r = 0; r < 4; ++r)
#pragma unroll
              for (int k = 0; k < 3; ++k) m = fmaxf(m, g[r][k]);
            const int ex = (int)((__float_as_uint(m) >> 23) & 0xffu) - 126;
            ce += ex;
            const float sc = __uint_as_float((unsigned)(127 - ex) << 23);
#pragma unroll
            for (int r = 0; r < 4; ++r)
#pragma unroll
              for (int k = 0; k < 3; ++k) g[r][k] *= sc;
          }
#pragma unroll
          for (int i = 0; i < 3; ++i) {
            float a = Erot[0][0][i] * g[0][0];
#pragma unroll
            for (int r = 0; r < 4; ++r)
#pragma unroll
              for (int k = 0; k < 3; ++k)
                if (r + k > 0) a = fmaf(Erot[r][k][i], g[r][k], a);
            o[i] = a;
          }
        }
      }
    }

    // ---- accumulate path score (uniform guards)
    if (fwd) {
#pragma unroll
      for (int kk = 0; kk < SPB; ++kk) {
        const int t = tb + kk;
        if (t < HALF) {
          emit += em[kk];
          if (kk > 0 || b > 0) trn += tr[kk];   // t==0 has no transition
        }
      }
    } else {
#pragma unroll
      for (int kk = 0; kk < SPB; ++kk) {
        if (255 - tb - kk >= HALF) { emit += em[kk]; trn += tr[kk]; }
      }
    }
  }

  // ---- exchange partials through LDS and combine in-block
  if (c < 3) {
#pragma unroll
    for (int k = 0; k < 3; ++k) comb[w][q][3 * c + k] = o[k];
  } else {
    comb[w][q][9]  = (float)ce;
    comb[w][q][10] = fwd ? (emit + trn + initv[plr[0]])
                         : (emit + trn);
  }
  __syncthreads();

  if (tid < SPW) {
    float dot = 0.f;
#pragma unroll
    for (int i = 0; i < 9; ++i)
      dot = fmaf(comb[0][tid][i], comb[1][tid][i], dot);
    const float score =
        (__builtin_amdgcn_logf(dot) + comb[0][tid][9] + comb[1][tid][9]) * LN2f;
    out[seq0 + tid] = score - (comb[0][tid][10] + comb[1][tid][10]);
  }
}

extern "C" void kernel_launch(void* const* d_in, const int* in_sizes, int n_in,
                              void* d_out, int out_size, void* d_ws, size_t ws_size,
                              hipStream_t stream) {
  (void)in_sizes; (void)n_in; (void)out_size; (void)d_ws; (void)ws_size;
  const float* xg    = (const float*)d_in[0];
  const int*   path  = (const int*)d_in[1];
  const float* tran  = (const float*)d_in[2];
  const float* initv = (const float*)d_in[3];
  float* out = (float*)d_out;

  crf_fused<<<NBLOCKS, 128, 0, stream>>>(xg, path, tran, initv, out);
}

// Round 4
// 136.971 us; speedup vs baseline: 1.0621x; 1.0619x over previous
//
#include <hip/hip_runtime.h>

// SimpleCRFHead R9: R5 split structure (proven 44.5us+2.5us) with doubled
// TLP: SPW 16->8, 2048 blocks x 64 threads -> 2 waves/SIMD machine-wide.
// Per-wave instruction stream unchanged (upper 8 quads exec-masked inert);
// total issue doubles but co-resident waves hide each other's dependency
// stalls (R8 showed VALUBusy 24%, HBM 9%, stalls insensitive to LDS/vmcnt
// scheduling -> latency-bound at 1 wave/SIMD).
// Inert-quad safety: all LDS pointers clamped via qc=min(q,7); stores and
// p255 guarded. Math identical to R5 (absmax 0.0).

#define B_N 8192
#define L_N 256
#define SEQ_STRIDE 2304      // L_N * 9
#define HALF 128
#define SPB 6                // steps per x window
#define XW 54                // floats per seq per window
#define XSTRIDE 55           // odd -> conflict-free LDS banks
#define NBLK 22              // ceil(128/6)
#define PLS 129              // path LDS row stride
#define SPW 8                // seqs per wave (was 16)
#define NDIR_BLOCKS (B_N / SPW)   // 1024 per direction

#define LOG2E 1.44269504088896340736f
#define LN2f  0.69314718055994530942f

// quad_perm rotate-left-by-r: lane c receives quad-lane (c+r)&3
#define QP1 57    // perm(1,2,3,0)
#define QP2 78    // perm(2,3,0,1)
#define QP3 147   // perm(3,0,1,2)
#define QROT(src, CTRL) \
  __int_as_float(__builtin_amdgcn_mov_dpp(__float_as_int(src), CTRL, 0xf, 0xf, 0))

__device__ __forceinline__ void gl_lds4(const void* g, void* l) {
  __builtin_amdgcn_global_load_lds(
      (const __attribute__((address_space(1))) void*)g,
      (__attribute__((address_space(3))) void*)l, 4, 0, 0);
}

__device__ __forceinline__ float fexp(float x) {
  return __builtin_amdgcn_exp2f(x * LOG2E);   // v_exp_f32 = 2^x
}

__global__ __launch_bounds__(64, 2) void crf_half(
    const float* __restrict__ xg, const int* __restrict__ path,
    const float* __restrict__ tran, const float* __restrict__ initv,
    float* __restrict__ ws)
{
  __shared__ float lx[2][SPW * XSTRIDE];  // 3520 B
  __shared__ int   pl[SPW * PLS];         // 4128 B
  __shared__ int   pl255[SPW];
  __shared__ float ltran[81];             // ~8.1 KB total -> >=8 blocks/CU

  const int lane = threadIdx.x;
  const int c = lane & 3;                 // quad slot (state group)
  const int q = lane >> 2;                // seq slot within wave (0..15)
  const int qc = (q < SPW) ? q : (SPW - 1);   // clamp inert upper quads
  const bool fwd = (int)blockIdx.x < NDIR_BLOCKS;
  const int seq0 = (fwd ? blockIdx.x : blockIdx.x - NDIR_BLOCKS) * SPW;

  for (int i = lane; i < 81; i += 64) ltran[i] = tran[i];

  // ---- stage path rows (gl_lds, coalesced 64-wide)
  {
    const int t0 = fwd ? 0 : 127;
#pragma unroll
    for (int r = 0; r < SPW; ++r) {
      const int* g = path + (size_t)(seq0 + r) * L_N + t0 + lane;
      gl_lds4(g,      &pl[r * PLS]);
      gl_lds4(g + 64, &pl[r * PLS + 64]);
    }
  }
  if (!fwd && lane < SPW)
    pl255[lane] = path[(size_t)(seq0 + lane) * L_N + 255];

  // ---- stage x window 0
  if (lane < XW) {
    const int fb = fwd ? 0 : (SEQ_STRIDE - XW);
#pragma unroll
    for (int r = 0; r < SPW; ++r)
      gl_lds4(xg + (size_t)(seq0 + r) * SEQ_STRIDE + fb + lane,
              &lx[0][r * XSTRIDE]);
  }

  // ---- rotation-ordered transition coefficients (prologue only)
  // fwd: out_i = sum_j E[i][j]*st[j], E[i][j]=e^{tran[j*9+i]}
  // bwd: out_i = sum_j E[i][j]*w[j],  E[i][j]=e^{tran[i*9+j]}
  float Erot[4][3][3];
#pragma unroll
  for (int r = 0; r < 4; ++r)
#pragma unroll
    for (int k = 0; k < 3; ++k)
#pragma unroll
      for (int i = 0; i < 3; ++i) {
        const int ig = 3 * c + i;
        const int jg = 3 * ((c + r) & 3) + k;
        float v = 0.f;
        if (ig < 9 && jg < 9)
          v = fexp(fwd ? tran[jg * 9 + ig] : tran[ig * 9 + jg]);
        Erot[r][k][i] = v;
      }

  float o[3];                 // own 3 states (c==3: always 0)
  float emit = 0.f, trn = 0.f;
  int ce = 0, pcur = 0;

  if (!fwd) {
#pragma unroll
    for (int k = 0; k < 3; ++k) o[k] = (c < 3) ? 1.f : 0.f;
    pcur = pl255[qc];         // p_255
  }

  const int myoff = (c == 3) ? 0 : 3 * c;   // c==3 reads safe dummy region

#pragma unroll 1
  for (int b = 0; b < NBLK; ++b) {
    asm volatile("s_waitcnt vmcnt(0)" ::: "memory");  // window b staged

    // prefetch window b+1
    if (b + 1 < NBLK && lane < XW) {
      const int fb = fwd ? (b + 1) * XW : (SEQ_STRIDE - XW * (b + 2));
      float* dst = &lx[(b + 1) & 1][0];
#pragma unroll
      for (int r = 0; r < SPW; ++r)
        gl_lds4(xg + (size_t)(seq0 + r) * SEQ_STRIDE + fb + lane,
                dst + r * XSTRIDE);
    }

    const float* lxq = &lx[b & 1][qc * XSTRIDE];

    // ---- own-state exps for the whole window (3 per step)
    float e[SPB * 3];
#pragma unroll
    for (int tt = 0; tt < SPB; ++tt)
#pragma unroll
      for (int k = 0; k < 3; ++k)
        e[tt * 3 + k] = fexp(lxq[tt * 9 + myoff + k]);

    if (fwd) {
#pragma unroll
      for (int kk = 0; kk < SPB; ++kk) {
        const int t = b * SPB + kk;
        if (t < HALF) {
          if (t == 0) {
#pragma unroll
            for (int k = 0; k < 3; ++k)
              o[k] = (c < 3) ? fexp(initv[3 * c + k] + lxq[myoff + k]) : 0.f;
            pcur = pl[qc * PLS];
            emit = lxq[pcur];
          } else {
            // exchange st -> replicated g[r][k] = st[3*((c+r)&3)+k]
            float g[4][3];
#pragma unroll
            for (int k = 0; k < 3; ++k) {
              g[0][k] = o[k];
              g[1][k] = QROT(o[k], QP1);
              g[2][k] = QROT(o[k], QP2);
              g[3][k] = QROT(o[k], QP3);
            }
            if (kk == 0 && b > 0) {   // rescale once per window (6 steps)
              float m = g[0][0];
#pragma unroll
              for (int r = 0; r < 4; ++r)
#pragma unroll
                for (int k = 0; k < 3; ++k) m = fmaxf(m, g[r][k]);
              const int ex = (int)((__float_as_uint(m) >> 23) & 0xffu) - 126;
              ce += ex;
              const float sc = __uint_as_float((unsigned)(127 - ex) << 23);
#pragma unroll
              for (int r = 0; r < 4; ++r)
#pragma unroll
                for (int k = 0; k < 3; ++k) g[r][k] *= sc;
            }
            float out[3];
#pragma unroll
            for (int i = 0; i < 3; ++i) {
              float a = Erot[0][0][i] * g[0][0];
#pragma unroll
              for (int r = 0; r < 4; ++r)
#pragma unroll
                for (int k = 0; k < 3; ++k)
                  if (r + k > 0) a = fmaf(Erot[r][k][i], g[r][k], a);
              out[i] = a;
            }
            // path score (quad-uniform LDS broadcasts)
            const int p = pl[qc * PLS + t];
            emit += lxq[kk * 9 + p];
            trn  += ltran[pcur * 9 + p];
            pcur = p;
#pragma unroll
            for (int i = 0; i < 3; ++i) o[i] = out[i] * e[kk * 3 + i];
          }
        }
      }
    } else {
#pragma unroll
      for (int kk = 0; kk < SPB; ++kk) {
        const int t = 255 - b * SPB - kk;
        if (t >= HALF) {
          const int tt = SPB - 1 - kk;
          float w[3];
#pragma unroll
          for (int k = 0; k < 3; ++k) w[k] = e[tt * 3 + k] * o[k];
          float g[4][3];
#pragma unroll
          for (int k = 0; k < 3; ++k) {
            g[0][k] = w[k];
            g[1][k] = QROT(w[k], QP1);
            g[2][k] = QROT(w[k], QP2);
            g[3][k] = QROT(w[k], QP3);
          }
          if (kk == 0 && b > 0) {
            float m = g[0][0];
#pragma unroll
            for (int r = 0; r < 4; ++r)
#pragma unroll
              for (int k = 0; k < 3; ++k) m = fmaxf(m, g[r][k]);
            const int ex = (int)((__float_as_uint(m) >> 23) & 0xffu) - 126;
            ce += ex;
            const float sc = __uint_as_float((unsigned)(127 - ex) << 23);
#pragma unroll
            for (int r = 0; r < 4; ++r)
#pragma unroll
              for (int k = 0; k < 3; ++k) g[r][k] *= sc;
          }
#pragma unroll
          for (int i = 0; i < 3; ++i) {
            float a = Erot[0][0][i] * g[0][0];
#pragma unroll
            for (int r = 0; r < 4; ++r)
#pragma unroll
              for (int k = 0; k < 3; ++k)
                if (r + k > 0) a = fmaf(Erot[r][k][i], g[r][k], a);
            o[i] = a;
          }
          // path score: emit for t, tran pair (p_{t-1}, p_t)
          emit += lxq[tt * 9 + pcur];
          const int pm = pl[qc * PLS + (t - 1 - 127)];
          trn += ltran[pm * 9 + pcur];
          pcur = pm;
        }
      }
    }
  }

  // ---- write partials (field-major); inert upper quads store nothing
  if (q < SPW) {
    const int sq = seq0 + q;
    float* wp = ws + sq;
    if (fwd) {
      if (c < 3) {
#pragma unroll
        for (int k = 0; k < 3; ++k) wp[(3 * c + k) * B_N] = o[k];
      } else {
        wp[9 * B_N] = (float)ce;
        const int p0 = pl[q * PLS];
        wp[10 * B_N] = emit + trn + initv[p0];
      }
    } else {
      if (c < 3) {
#pragma unroll
        for (int k = 0; k < 3; ++k) wp[(11 + 3 * c + k) * B_N] = o[k];
      } else {
        wp[20 * B_N] = (float)ce;
        wp[21 * B_N] = emit + trn;
      }
    }
  }
}

__global__ __launch_bounds__(256) void crf_combine(
    const float* __restrict__ ws, float* __restrict__ out)
{
  const int s = blockIdx.x * 256 + threadIdx.x;
  float dot = 0.f;
#pragma unroll
  for (int i = 0; i < 9; ++i)
    dot = fmaf(ws[i * B_N + s], ws[(11 + i) * B_N + s], dot);
  const float score =
      (__builtin_amdgcn_logf(dot) + ws[9 * B_N + s] + ws[20 * B_N + s]) * LN2f;
  out[s] = score - (ws[10 * B_N + s] + ws[21 * B_N + s]);
}

extern "C" void kernel_launch(void* const* d_in, const int* in_sizes, int n_in,
                              void* d_out, int out_size, void* d_ws, size_t ws_size,
                              hipStream_t stream) {
  (void)in_sizes; (void)n_in; (void)out_size; (void)ws_size;
  const float* xg    = (const float*)d_in[0];
  const int*   path  = (const int*)d_in[1];
  const float* tran  = (const float*)d_in[2];
  const float* initv = (const float*)d_in[3];
  float* ws  = (float*)d_ws;    // 22*8192*4 = 721 KB
  float* out = (float*)d_out;

  crf_half<<<2 * NDIR_BLOCKS, 64, 0, stream>>>(xg, path, tran, initv, ws);
  crf_combine<<<B_N / 256, 256, 0, stream>>>(ws, out);
}